// Round 11
// baseline (192.536 us; speedup 1.0000x reference)
//
#include <hip/hip_runtime.h>

// MaxUnpooling2D scatter-add, round 11: MEASUREMENT ROUND.
// Exact R9 code (best: 153.6us) but bin_sort launched TWICE (idempotent) to
// expose the K1/K2 split: dur = 2*K1 + K2, and R9 gave K1 + K2 = 153.6us.
//
// dest(in-batch, 22b) = (m & ~255) | c, m = y<<15|x<<8|f (Ho=Wo=128, C=256).
// region r = dest>>13 = m>>13 (512/batch x 8192 floats = 32 KB).
// record = (dest & 8191) << 19 | (f32bits + 0x1000) >> 13   (19-bit float).

typedef float __attribute__((ext_vector_type(4))) f32x4;
typedef int   __attribute__((ext_vector_type(4))) i32x4;
typedef unsigned int u32;
typedef u32 __attribute__((ext_vector_type(4))) u32x4;

constexpr int NIN    = 16 * 64 * 64 * 256;  // 2^24 elements
constexpr int NBIN   = 512;                 // regions per batch
constexpr int REGION = 8192;                // floats per region (32 KB)
constexpr int RPB    = 16384;               // records per K1 block
constexpr int NBLK1  = NIN / RPB;           // 1024
constexpr int TPB1   = 512;
constexpr int SRCB   = (1 << 20) / RPB;     // 64 source blocks per batch
constexpr int TPB2   = 512;
constexpr int NBLK2  = 16 * NBIN;           // 8192

// ---------------- K1: single-pass block-local counting sort ----------------
__global__ __launch_bounds__(TPB1, 4) void bin_sort(
    const f32x4* __restrict__ upd, const i32x4* __restrict__ msk,
    u32* __restrict__ recs, u32* __restrict__ packed)
{
    __shared__ int hist[NBIN];
    __shared__ int pscan[NBIN];
    __shared__ int cursor[NBIN];
    __shared__ u32 staged[RPB];             // 64 KB

    const int tid = threadIdx.x;
    const int blk = blockIdx.x;
    const int v0  = blk * (RPB / 4);

    hist[tid] = 0;                          // NBIN == TPB1
    __syncthreads();

    // load once (NT), pack into registers, histogram
    u32 pk[32]; int bin[32];
#pragma unroll
    for (int j = 0; j < 8; ++j) {
        const int t = v0 + tid + j * TPB1;
        i32x4 m = __builtin_nontemporal_load(&msk[t]);
        f32x4 u = __builtin_nontemporal_load(&upd[t]);
        const int c = (t << 2) & 255;
        {
            const u32 d = (u32)((m.x & ~255) | c);
            bin[j*4+0] = (int)(d >> 13);
            pk[j*4+0] = ((d & 8191) << 19) | ((__float_as_uint(u.x) + 0x1000) >> 13);
        }
        {
            const u32 d = (u32)((m.y & ~255) | (c + 1));
            bin[j*4+1] = (int)(d >> 13);
            pk[j*4+1] = ((d & 8191) << 19) | ((__float_as_uint(u.y) + 0x1000) >> 13);
        }
        {
            const u32 d = (u32)((m.z & ~255) | (c + 2));
            bin[j*4+2] = (int)(d >> 13);
            pk[j*4+2] = ((d & 8191) << 19) | ((__float_as_uint(u.z) + 0x1000) >> 13);
        }
        {
            const u32 d = (u32)((m.w & ~255) | (c + 3));
            bin[j*4+3] = (int)(d >> 13);
            pk[j*4+3] = ((d & 8191) << 19) | ((__float_as_uint(u.w) + 0x1000) >> 13);
        }
#pragma unroll
        for (int e = 0; e < 4; ++e)
            atomicAdd(&hist[bin[j*4+e]], 1);
    }
    __syncthreads();

    // exclusive prefix over 512 bins (Hillis-Steele, 1 bin/thread)
    const int h = hist[tid];
    pscan[tid] = h;
    __syncthreads();
    for (int d = 1; d < NBIN; d <<= 1) {
        int v = 0;
        if (tid >= d) v = pscan[tid - d];
        __syncthreads();
        pscan[tid] += v;
        __syncthreads();
    }
    const int excl = pscan[tid] - h;
    cursor[tid] = excl;
    // block-major table: coalesced 2 KB store (K2's strided read is L2-hot)
    packed[blk * NBIN + tid] = ((u32)excl << 16) | (u32)h;
    __syncthreads();

    // scatter from registers into staged, sorted by region
#pragma unroll
    for (int k = 0; k < 32; ++k)
        staged[atomicAdd(&cursor[bin[k]], 1)] = pk[k];
    __syncthreads();

    // coalesced copy staged -> global segment (blk * 64 KB)
    u32x4* sg = (u32x4*)staged;
    u32x4* gg = (u32x4*)(recs + (size_t)blk * RPB);
#pragma unroll
    for (int j = 0; j < RPB / 4 / TPB1; ++j)
        gg[tid + j * TPB1] = sg[tid + j * TPB1];
}

// ---------------- K2: per-region LDS accumulate + write-out ----------------
__global__ __launch_bounds__(TPB2, 8) void accumulate(
    const u32* __restrict__ recs, const u32* __restrict__ packed,
    float* __restrict__ out)
{
    __shared__ float region[REGION];        // 32 KB
    __shared__ int spre[SRCB];              // inclusive scan of counts
    __shared__ int base[SRCB];              // recs base minus exclusive prefix

    const int tid = threadIdx.x;
    // XCD-bijective swizzle: consecutive logical regions share an XCD L2.
    const int lid = ((blockIdx.x & 7) << 10) | (blockIdx.x >> 3);
    const int b = lid >> 9;                 // batch
    const int r = lid & (NBIN - 1);         // region

    f32x4* rv = (f32x4*)region;
#pragma unroll
    for (int j = 0; j < REGION / 4 / TPB2; ++j)
        rv[tid + j * TPB2] = f32x4{0.f, 0.f, 0.f, 0.f};

    if (tid < SRCB) {                       // wave 0 only: shuffle scan
        const u32 p = packed[(size_t)(b * SRCB + tid) * NBIN + r];
        const int cnt = (int)(p & 0xFFFF);
        const int off = (int)(p >> 16);
        int s = cnt;
#pragma unroll
        for (int d = 1; d < SRCB; d <<= 1) {
            const int v = __shfl_up(s, d, 64);
            if (tid >= d) s += v;
        }
        spre[tid] = s;
        base[tid] = (b * SRCB + tid) * RPB + off - (s - cnt);
    }
    __syncthreads();

    const int T = spre[SRCB - 1];

    // gather + LDS accumulate; 6-step branchless lower-bound per record, x4 ILP
    for (int w0 = tid; w0 < T; w0 += 4 * TPB2) {
        const int w1 = w0 + TPB2, w2 = w0 + 2 * TPB2, w3 = w0 + 3 * TPB2;
        const bool g1 = w1 < T, g2 = w2 < T, g3 = w3 < T;
        const int v1 = g1 ? w1 : 0, v2 = g2 ? w2 : 0, v3 = g3 ? w3 : 0;
        int k0 = 0, k1 = 0, k2 = 0, k3 = 0;
#pragma unroll
        for (int d = 32; d >= 1; d >>= 1) {
            if (spre[k0 + d - 1] <= w0) k0 += d;
            if (spre[k1 + d - 1] <= v1) k1 += d;
            if (spre[k2 + d - 1] <= v2) k2 += d;
            if (spre[k3 + d - 1] <= v3) k3 += d;
        }
        const u32 p0 = recs[base[k0] + w0];
        const u32 p1 = recs[base[k1] + v1];
        const u32 p2 = recs[base[k2] + v2];
        const u32 p3 = recs[base[k3] + v3];
        atomicAdd(&region[p0 >> 19], __uint_as_float((p0 & 0x7FFFF) << 13));
        if (g1) atomicAdd(&region[p1 >> 19], __uint_as_float((p1 & 0x7FFFF) << 13));
        if (g2) atomicAdd(&region[p2 >> 19], __uint_as_float((p2 & 0x7FFFF) << 13));
        if (g3) atomicAdd(&region[p3 >> 19], __uint_as_float((p3 & 0x7FFFF) << 13));
    }
    __syncthreads();

    // nontemporal write-out: output never re-read; keep L2/L3 for the gather
    f32x4* og = (f32x4*)(out + ((size_t)b << 22) + ((size_t)r << 13));
#pragma unroll
    for (int j = 0; j < REGION / 4 / TPB2; ++j)
        __builtin_nontemporal_store(rv[tid + j * TPB2], &og[tid + j * TPB2]);
}

// ---------------- fallback (ws too small): R1 atomic scatter ----------------
__global__ __launch_bounds__(256) void unpool_scatter(
    const f32x4* __restrict__ upd, const i32x4* __restrict__ msk,
    float* __restrict__ out)
{
    const int t = blockIdx.x * 256 + threadIdx.x;
    const int e = t << 2;
    f32x4 u = upd[t];
    i32x4 m = msk[t];
    const int b = e >> 20;
    const int c = e & 255;
    float* ob = out + ((long long)b << 22);
    atomicAdd(ob + ((m.x & ~255) | (c    )), u.x);
    atomicAdd(ob + ((m.y & ~255) | (c + 1)), u.y);
    atomicAdd(ob + ((m.z & ~255) | (c + 2)), u.z);
    atomicAdd(ob + ((m.w & ~255) | (c + 3)), u.w);
}

extern "C" void kernel_launch(void* const* d_in, const int* in_sizes, int n_in,
                              void* d_out, int out_size, void* d_ws, size_t ws_size,
                              hipStream_t stream) {
    const f32x4* upd = (const f32x4*)d_in[0];
    const i32x4* msk = (const i32x4*)d_in[1];
    float* out = (float*)d_out;

    constexpr size_t REC_BYTES = (size_t)NIN * 4;                    // 64 MiB
    constexpr size_t PCK_BYTES = (size_t)NBLK1 * NBIN * sizeof(u32); // 2 MiB

    if (ws_size >= REC_BYTES + PCK_BYTES) {
        u32* recs = (u32*)d_ws;
        u32* packed = (u32*)((char*)d_ws + REC_BYTES);
        // MEASUREMENT: launch K1 twice (idempotent). dur = 2*K1 + K2.
        bin_sort<<<NBLK1, TPB1, 0, stream>>>(upd, msk, recs, packed);
        bin_sort<<<NBLK1, TPB1, 0, stream>>>(upd, msk, recs, packed);
        accumulate<<<NBLK2, TPB2, 0, stream>>>(recs, packed, out);
    } else {
        (void)hipMemsetAsync(out, 0, (size_t)out_size * sizeof(float), stream);
        unpool_scatter<<<NIN / 4 / 256, 256, 0, stream>>>(upd, msk, out);
    }
}

// Round 12
// 144.900 us; speedup vs baseline: 1.3288x; 1.3288x over previous
//
#include <hip/hip_runtime.h>

// MaxUnpooling2D scatter-add, round 12: two-phase binning, zero global atomics.
// vs R9 (best, 153.6us = K1 39 + K2 115): K2 gather rewritten wave-per-chunk:
// no per-record binary search, no prefix scan; wave wv handles chunks
// wv*8..wv*8+7, lanes read consecutive records (coalesced <=256B) and
// LDS-atomicAdd. K1 unchanged.
//
// dest(in-batch, 22b) = (m & ~255) | c, m = y<<15|x<<8|f (Ho=Wo=128, C=256).
// region r = dest>>13 = m>>13 (512/batch x 8192 floats = 32 KB).
// record = (dest & 8191) << 19 | (f32bits + 0x1000) >> 13   (19-bit float).

typedef float __attribute__((ext_vector_type(4))) f32x4;
typedef int   __attribute__((ext_vector_type(4))) i32x4;
typedef unsigned int u32;
typedef u32 __attribute__((ext_vector_type(4))) u32x4;

constexpr int NIN    = 16 * 64 * 64 * 256;  // 2^24 elements
constexpr int NBIN   = 512;                 // regions per batch
constexpr int REGION = 8192;                // floats per region (32 KB)
constexpr int RPB    = 16384;               // records per K1 block
constexpr int NBLK1  = NIN / RPB;           // 1024
constexpr int TPB1   = 512;
constexpr int SRCB   = (1 << 20) / RPB;     // 64 source blocks per batch
constexpr int TPB2   = 512;
constexpr int NBLK2  = 16 * NBIN;           // 8192

// ---------------- K1: single-pass block-local counting sort ----------------
__global__ __launch_bounds__(TPB1, 4) void bin_sort(
    const f32x4* __restrict__ upd, const i32x4* __restrict__ msk,
    u32* __restrict__ recs, u32* __restrict__ packed)
{
    __shared__ int hist[NBIN];
    __shared__ int pscan[NBIN];
    __shared__ int cursor[NBIN];
    __shared__ u32 staged[RPB];             // 64 KB

    const int tid = threadIdx.x;
    const int blk = blockIdx.x;
    const int v0  = blk * (RPB / 4);

    hist[tid] = 0;                          // NBIN == TPB1
    __syncthreads();

    // load once (NT), pack into registers, histogram
    u32 pk[32]; int bin[32];
#pragma unroll
    for (int j = 0; j < 8; ++j) {
        const int t = v0 + tid + j * TPB1;
        i32x4 m = __builtin_nontemporal_load(&msk[t]);
        f32x4 u = __builtin_nontemporal_load(&upd[t]);
        const int c = (t << 2) & 255;
        {
            const u32 d = (u32)((m.x & ~255) | c);
            bin[j*4+0] = (int)(d >> 13);
            pk[j*4+0] = ((d & 8191) << 19) | ((__float_as_uint(u.x) + 0x1000) >> 13);
        }
        {
            const u32 d = (u32)((m.y & ~255) | (c + 1));
            bin[j*4+1] = (int)(d >> 13);
            pk[j*4+1] = ((d & 8191) << 19) | ((__float_as_uint(u.y) + 0x1000) >> 13);
        }
        {
            const u32 d = (u32)((m.z & ~255) | (c + 2));
            bin[j*4+2] = (int)(d >> 13);
            pk[j*4+2] = ((d & 8191) << 19) | ((__float_as_uint(u.z) + 0x1000) >> 13);
        }
        {
            const u32 d = (u32)((m.w & ~255) | (c + 3));
            bin[j*4+3] = (int)(d >> 13);
            pk[j*4+3] = ((d & 8191) << 19) | ((__float_as_uint(u.w) + 0x1000) >> 13);
        }
#pragma unroll
        for (int e = 0; e < 4; ++e)
            atomicAdd(&hist[bin[j*4+e]], 1);
    }
    __syncthreads();

    // exclusive prefix over 512 bins (Hillis-Steele, 1 bin/thread)
    const int h = hist[tid];
    pscan[tid] = h;
    __syncthreads();
    for (int d = 1; d < NBIN; d <<= 1) {
        int v = 0;
        if (tid >= d) v = pscan[tid - d];
        __syncthreads();
        pscan[tid] += v;
        __syncthreads();
    }
    const int excl = pscan[tid] - h;
    cursor[tid] = excl;
    // block-major table: coalesced 2 KB store (K2's strided read is L2-hot)
    packed[blk * NBIN + tid] = ((u32)excl << 16) | (u32)h;
    __syncthreads();

    // scatter from registers into staged, sorted by region
#pragma unroll
    for (int k = 0; k < 32; ++k)
        staged[atomicAdd(&cursor[bin[k]], 1)] = pk[k];
    __syncthreads();

    // coalesced copy staged -> global segment (blk * 64 KB)
    u32x4* sg = (u32x4*)staged;
    u32x4* gg = (u32x4*)(recs + (size_t)blk * RPB);
#pragma unroll
    for (int j = 0; j < RPB / 4 / TPB1; ++j)
        gg[tid + j * TPB1] = sg[tid + j * TPB1];
}

// ---------------- K2: wave-per-chunk gather + LDS accumulate ----------------
__global__ __launch_bounds__(TPB2, 8) void accumulate(
    const u32* __restrict__ recs, const u32* __restrict__ packed,
    float* __restrict__ out)
{
    __shared__ float region[REGION];        // 32 KB

    const int tid  = threadIdx.x;
    const int lane = tid & 63;
    const int wv   = tid >> 6;              // 0..7
    // XCD-bijective swizzle: consecutive logical regions share an XCD L2.
    const int lid = ((blockIdx.x & 7) << 10) | (blockIdx.x >> 3);
    const int b = lid >> 9;                 // batch
    const int r = lid & (NBIN - 1);         // region

    f32x4* rv = (f32x4*)region;
#pragma unroll
    for (int j = 0; j < REGION / 4 / TPB2; ++j)
        rv[tid + j * TPB2] = f32x4{0.f, 0.f, 0.f, 0.f};

    // each lane reads the packed (off,cnt) of chunk `lane` (L1-shared x8 waves)
    const u32 pl = packed[(size_t)(b * SRCB + lane) * NBIN + r];
    __syncthreads();                        // region zeroed before atomics

    // wave wv owns chunks wv*8 .. wv*8+7: issue 8 independent coalesced loads
    u32 rec[8]; int cnt[8]; u32 idx[8];
#pragma unroll
    for (int j = 0; j < 8; ++j) {
        const int k = (wv << 3) | j;
        const u32 pj = __shfl(pl, k, 64);
        cnt[j] = (int)(pj & 0xFFFF);
        idx[j] = (u32)((b * SRCB + k) * RPB) + (pj >> 16);
        rec[j] = recs[idx[j] + (lane < cnt[j] ? lane : 0)];  // safe overread
    }
#pragma unroll
    for (int j = 0; j < 8; ++j)
        if (lane < cnt[j])
            atomicAdd(&region[rec[j] >> 19],
                      __uint_as_float((rec[j] & 0x7FFFF) << 13));
    // rare tails (cnt > 64)
#pragma unroll
    for (int j = 0; j < 8; ++j)
        for (int i = 64 + lane; i < cnt[j]; i += 64) {
            const u32 p = recs[idx[j] + i];
            atomicAdd(&region[p >> 19], __uint_as_float((p & 0x7FFFF) << 13));
        }
    __syncthreads();

    // nontemporal write-out: output never re-read; keep L2/L3 for the gather
    f32x4* og = (f32x4*)(out + ((size_t)b << 22) + ((size_t)r << 13));
#pragma unroll
    for (int j = 0; j < REGION / 4 / TPB2; ++j)
        __builtin_nontemporal_store(rv[tid + j * TPB2], &og[tid + j * TPB2]);
}

// ---------------- fallback (ws too small): R1 atomic scatter ----------------
__global__ __launch_bounds__(256) void unpool_scatter(
    const f32x4* __restrict__ upd, const i32x4* __restrict__ msk,
    float* __restrict__ out)
{
    const int t = blockIdx.x * 256 + threadIdx.x;
    const int e = t << 2;
    f32x4 u = upd[t];
    i32x4 m = msk[t];
    const int b = e >> 20;
    const int c = e & 255;
    float* ob = out + ((long long)b << 22);
    atomicAdd(ob + ((m.x & ~255) | (c    )), u.x);
    atomicAdd(ob + ((m.y & ~255) | (c + 1)), u.y);
    atomicAdd(ob + ((m.z & ~255) | (c + 2)), u.z);
    atomicAdd(ob + ((m.w & ~255) | (c + 3)), u.w);
}

extern "C" void kernel_launch(void* const* d_in, const int* in_sizes, int n_in,
                              void* d_out, int out_size, void* d_ws, size_t ws_size,
                              hipStream_t stream) {
    const f32x4* upd = (const f32x4*)d_in[0];
    const i32x4* msk = (const i32x4*)d_in[1];
    float* out = (float*)d_out;

    constexpr size_t REC_BYTES = (size_t)NIN * 4;                    // 64 MiB
    constexpr size_t PCK_BYTES = (size_t)NBLK1 * NBIN * sizeof(u32); // 2 MiB

    if (ws_size >= REC_BYTES + PCK_BYTES + 4) {      // +4: guarded overread
        u32* recs = (u32*)d_ws;
        u32* packed = (u32*)((char*)d_ws + REC_BYTES);
        bin_sort<<<NBLK1, TPB1, 0, stream>>>(upd, msk, recs, packed);
        accumulate<<<NBLK2, TPB2, 0, stream>>>(recs, packed, out);
    } else {
        (void)hipMemsetAsync(out, 0, (size_t)out_size * sizeof(float), stream);
        unpool_scatter<<<NIN / 4 / 256, 256, 0, stream>>>(upd, msk, out);
    }
}